// Round 1
// baseline (1025.050 us; speedup 1.0000x reference)
//
#include <hip/hip_runtime.h>
#include <hip/hip_bf16.h>
#include <math.h>
#include <stdint.h>

// Problem constants (B=4, S=2048, H=1024, I=4096, E=8, K=2)
#define TOKENS 8192
#define HD 1024
#define ID 4096
#define NE 8
#define RMAX 17408   // 16384 + 8*128 worst-case padded rows
#define MAXT 136     // RMAX/128 max M-tiles

typedef __attribute__((ext_vector_type(8))) short short8v;
typedef __attribute__((ext_vector_type(4))) float f32x4;

typedef const __attribute__((address_space(1))) unsigned int* gas_u32p;
typedef __attribute__((address_space(3))) unsigned int* las_u32p;

__device__ __forceinline__ void stage16(const void* g, void* l) {
  __builtin_amdgcn_global_load_lds((gas_u32p)g, (las_u32p)l, 16, 0, 0);
}

// ---------------- weight fp32 -> bf16 convert ----------------
__global__ __launch_bounds__(256) void convert_kernel(const float* __restrict__ src,
                                                      __hip_bfloat16* __restrict__ dst) {
  size_t i = ((size_t)blockIdx.x * 256 + threadIdx.x) * 8;
  float4 a = ((const float4*)(src + i))[0];
  float4 b = ((const float4*)(src + i))[1];
  union { __hip_bfloat16 h[8]; int4 v; } u;
  u.h[0] = __float2bfloat16(a.x); u.h[1] = __float2bfloat16(a.y);
  u.h[2] = __float2bfloat16(a.z); u.h[3] = __float2bfloat16(a.w);
  u.h[4] = __float2bfloat16(b.x); u.h[5] = __float2bfloat16(b.y);
  u.h[6] = __float2bfloat16(b.z); u.h[7] = __float2bfloat16(b.w);
  *(int4*)(dst + i) = u.v;
}

// ---------------- router: logits (fp64 acc), top-2, weights; also h->bf16 ----------------
__global__ __launch_bounds__(256) void router_kernel(
    const float* __restrict__ h, const float* __restrict__ rw,
    __hip_bfloat16* __restrict__ hx, int* __restrict__ tidx,
    float* __restrict__ tw, int* __restrict__ cnt) {
  int wid = threadIdx.x >> 6, lane = threadIdx.x & 63;
  int t = blockIdx.x * 4 + wid;  // grid = TOKENS/4
  const float4* h4 = (const float4*)(h + (size_t)t * HD);
  float x[16];
  {
    float4 xa = h4[lane * 4 + 0], xb = h4[lane * 4 + 1], xc = h4[lane * 4 + 2], xd = h4[lane * 4 + 3];
    x[0] = xa.x; x[1] = xa.y; x[2] = xa.z; x[3] = xa.w;
    x[4] = xb.x; x[5] = xb.y; x[6] = xb.z; x[7] = xb.w;
    x[8] = xc.x; x[9] = xc.y; x[10] = xc.z; x[11] = xc.w;
    x[12] = xd.x; x[13] = xd.y; x[14] = xd.z; x[15] = xd.w;
  }
  union { __hip_bfloat16 hb[16]; int4 v[2]; } u;
#pragma unroll
  for (int j = 0; j < 16; j++) u.hb[j] = __float2bfloat16(x[j]);
  {
    int4* hxp = (int4*)(hx + (size_t)t * HD + lane * 16);
    hxp[0] = u.v[0]; hxp[1] = u.v[1];
  }
  double acc[NE];
#pragma unroll
  for (int e = 0; e < NE; e++) {
    const float4* w4 = (const float4*)(rw + e * HD);
    float4 wa = w4[lane * 4 + 0], wb = w4[lane * 4 + 1], wc = w4[lane * 4 + 2], wd = w4[lane * 4 + 3];
    double s = 0.0;
    s += (double)x[0] * wa.x + (double)x[1] * wa.y + (double)x[2] * wa.z + (double)x[3] * wa.w;
    s += (double)x[4] * wb.x + (double)x[5] * wb.y + (double)x[6] * wb.z + (double)x[7] * wb.w;
    s += (double)x[8] * wc.x + (double)x[9] * wc.y + (double)x[10] * wc.z + (double)x[11] * wc.w;
    s += (double)x[12] * wd.x + (double)x[13] * wd.y + (double)x[14] * wd.z + (double)x[15] * wd.w;
    acc[e] = s;
  }
#pragma unroll
  for (int off = 32; off >= 1; off >>= 1)
#pragma unroll
    for (int e = 0; e < NE; e++) acc[e] += __shfl_xor(acc[e], off, 64);
  if (lane == 0) {
    int i0 = 0; double l0 = acc[0];
#pragma unroll
    for (int e = 1; e < NE; e++) if (acc[e] > l0) { l0 = acc[e]; i0 = e; }
    int i1 = -1; double l1 = -1.0e300;
#pragma unroll
    for (int e = 0; e < NE; e++) if (e != i0 && acc[e] > l1) { l1 = acc[e]; i1 = e; }
    double r = exp(l1 - l0);  // <= 1
    float w0 = (float)(1.0 / (1.0 + r));
    float w1 = (float)(r / (1.0 + r));
    tidx[t * 2 + 0] = i0; tidx[t * 2 + 1] = i1;
    tw[t * 2 + 0] = w0;  tw[t * 2 + 1] = w1;
    atomicAdd(&cnt[i0], 1); atomicAdd(&cnt[i1], 1);
  }
}

// ---------------- offsets scan (pad each expert to 128 rows) ----------------
__global__ void scan_kernel(const int* __restrict__ cnt, int* __restrict__ ofs, int* __restrict__ cnt2) {
  if (threadIdx.x == 0) {
    int a = 0;
    for (int e = 0; e < NE; e++) { ofs[e] = a; a += (cnt[e] + 127) & ~127; }
    ofs[NE] = a;
  }
  if (threadIdx.x < NE) cnt2[threadIdx.x] = 0;
}

// ---------------- scatter token -> expert row lists ----------------
__global__ __launch_bounds__(256) void scatter_kernel(
    const int* __restrict__ tidx, const float* __restrict__ tw,
    const int* __restrict__ ofs, int* __restrict__ cnt2,
    int* __restrict__ rowmap, int* __restrict__ slots) {
  int t = blockIdx.x * 256 + threadIdx.x;  // grid = TOKENS/256
#pragma unroll
  for (int k = 0; k < 2; k++) {
    int e = tidx[t * 2 + k];
    int pos = atomicAdd(&cnt2[e], 1);
    int row = ofs[e] + pos;
    rowmap[row] = t;
    slots[t * 2 + k] = row;
  }
}

// ---------------- gather bf16 hidden rows into compacted A1 (zero pad rows) ----------------
__global__ __launch_bounds__(256) void gather_kernel(
    const __hip_bfloat16* __restrict__ hx, const int* __restrict__ rowmap,
    const int* __restrict__ ofs, __hip_bfloat16* __restrict__ A1) {
  int r = blockIdx.x * 4 + (threadIdx.x >> 6);
  int lane = threadIdx.x & 63;
  if (r >= ofs[NE]) return;
  int t = rowmap[r];
  int4* dst = (int4*)(A1 + (size_t)r * HD);
  if (t < 0) {
    int4 z = {0, 0, 0, 0};
    dst[lane * 2 + 0] = z; dst[lane * 2 + 1] = z;
  } else {
    const int4* src = (const int4*)(hx + (size_t)t * HD);
    dst[lane * 2 + 0] = src[lane * 2 + 0];
    dst[lane * 2 + 1] = src[lane * 2 + 1];
  }
}

// ---------------- GEMM1: act = silu(A1 @ Wg[e]^T) * (A1 @ Wu[e]^T), bf16 out ----------------
// 128x128 tile, BK=64, 4 waves (2x2), 16x16x32 bf16 MFMA, gate+up fused.
__global__ __launch_bounds__(256, 2) void gemm1_kernel(
    const __hip_bfloat16* __restrict__ A1, const __hip_bfloat16* __restrict__ Wg,
    const __hip_bfloat16* __restrict__ Wu, const int* __restrict__ ofs,
    __hip_bfloat16* __restrict__ act) {
  __shared__ __hip_bfloat16 sA[128 * 64];
  __shared__ __hip_bfloat16 sG[128 * 64];
  __shared__ __hip_bfloat16 sU[128 * 64];
  const int tm = blockIdx.x, tn = blockIdx.y;
  const int Rtot = ofs[NE];
  const int row0 = tm * 128;
  if (row0 >= Rtot) return;
  int e = 0;
#pragma unroll
  for (int i = 1; i < NE; i++) e += (row0 >= ofs[i]);
  const int t = threadIdx.x, wid = t >> 6, lane = t & 63;
  const int wm = wid >> 1, wn = wid & 1;
  const int fr = lane & 15, fk = (lane >> 4) << 3;

  const char* gA = (const char*)(A1 + (size_t)row0 * HD);
  const char* gG = (const char*)(Wg + ((size_t)e * ID + tn * 128) * HD);
  const char* gU = (const char*)(Wu + ((size_t)e * ID + tn * 128) * HD);

  int srow[4], scol[4];
#pragma unroll
  for (int i = 0; i < 4; i++) { int li = (i * 256 + t) * 16; srow[i] = li >> 7; scol[i] = li & 127; }

  f32x4 accG[4][4], accU[4][4];
#pragma unroll
  for (int m = 0; m < 4; m++)
#pragma unroll
    for (int n = 0; n < 4; n++) { accG[m][n] = (f32x4)(0.0f); accU[m][n] = (f32x4)(0.0f); }

  for (int kt = 0; kt < HD / 64; kt++) {
    const int kb = kt * 128;  // byte offset along K (64 bf16)
#pragma unroll
    for (int i = 0; i < 4; i++) {
      size_t go = (size_t)srow[i] * 2048 + kb + scol[i];
      stage16(gA + go, (char*)sA + i * 4096 + wid * 1024);
      stage16(gG + go, (char*)sG + i * 4096 + wid * 1024);
      stage16(gU + go, (char*)sU + i * 4096 + wid * 1024);
    }
    __syncthreads();
#pragma unroll
    for (int kk = 0; kk < 64; kk += 32) {
      short8v av[4], bg[4], bu[4];
#pragma unroll
      for (int m = 0; m < 4; m++)
        av[m] = *(const short8v*)(sA + (wm * 64 + m * 16 + fr) * 64 + kk + fk);
#pragma unroll
      for (int n = 0; n < 4; n++) {
        bg[n] = *(const short8v*)(sG + (wn * 64 + n * 16 + fr) * 64 + kk + fk);
        bu[n] = *(const short8v*)(sU + (wn * 64 + n * 16 + fr) * 64 + kk + fk);
      }
#pragma unroll
      for (int m = 0; m < 4; m++)
#pragma unroll
        for (int n = 0; n < 4; n++) {
          accG[m][n] = __builtin_amdgcn_mfma_f32_16x16x32_bf16(av[m], bg[n], accG[m][n], 0, 0, 0);
          accU[m][n] = __builtin_amdgcn_mfma_f32_16x16x32_bf16(av[m], bu[n], accU[m][n], 0, 0, 0);
        }
    }
    __syncthreads();
  }
  // epilogue: act = bf16(silu(g) * u). C layout: col=lane&15, row=(lane>>4)*4+i.
  const int rb = row0 + wm * 64 + ((lane >> 4) << 2);
  const int cb = tn * 128 + wn * 64 + fr;
#pragma unroll
  for (int m = 0; m < 4; m++)
#pragma unroll
    for (int i = 0; i < 4; i++) {
      int r = rb + m * 16 + i;
      __hip_bfloat16* dst = act + (size_t)r * ID + cb;
#pragma unroll
      for (int n = 0; n < 4; n++) {
        float g = accG[m][n][i], uu = accU[m][n][i];
        float s = g / (1.0f + __expf(-g));
        dst[n * 16] = __float2bfloat16(s * uu);
      }
    }
}

// ---------------- GEMM2: y = act @ Wd[e]^T (fp32 out to ybuf) ----------------
__global__ __launch_bounds__(256, 2) void gemm2_kernel(
    const __hip_bfloat16* __restrict__ act, const __hip_bfloat16* __restrict__ Wd,
    const int* __restrict__ ofs, float* __restrict__ ybuf) {
  __shared__ __hip_bfloat16 sA[128 * 64];
  __shared__ __hip_bfloat16 sB[128 * 64];
  const int tm = blockIdx.x, tn = blockIdx.y;
  const int Rtot = ofs[NE];
  const int row0 = tm * 128;
  if (row0 >= Rtot) return;
  int e = 0;
#pragma unroll
  for (int i = 1; i < NE; i++) e += (row0 >= ofs[i]);
  const int t = threadIdx.x, wid = t >> 6, lane = t & 63;
  const int wm = wid >> 1, wn = wid & 1;
  const int fr = lane & 15, fk = (lane >> 4) << 3;

  const char* gA = (const char*)(act + (size_t)row0 * ID);
  const char* gB = (const char*)(Wd + ((size_t)e * HD + tn * 128) * ID);

  int srow[4], scol[4];
#pragma unroll
  for (int i = 0; i < 4; i++) { int li = (i * 256 + t) * 16; srow[i] = li >> 7; scol[i] = li & 127; }

  f32x4 acc[4][4];
#pragma unroll
  for (int m = 0; m < 4; m++)
#pragma unroll
    for (int n = 0; n < 4; n++) acc[m][n] = (f32x4)(0.0f);

  for (int kt = 0; kt < ID / 64; kt++) {
    const int kb = kt * 128;
#pragma unroll
    for (int i = 0; i < 4; i++) {
      size_t go = (size_t)srow[i] * 8192 + kb + scol[i];
      stage16(gA + go, (char*)sA + i * 4096 + wid * 1024);
      stage16(gB + go, (char*)sB + i * 4096 + wid * 1024);
    }
    __syncthreads();
#pragma unroll
    for (int kk = 0; kk < 64; kk += 32) {
      short8v av[4], bv[4];
#pragma unroll
      for (int m = 0; m < 4; m++)
        av[m] = *(const short8v*)(sA + (wm * 64 + m * 16 + fr) * 64 + kk + fk);
#pragma unroll
      for (int n = 0; n < 4; n++)
        bv[n] = *(const short8v*)(sB + (wn * 64 + n * 16 + fr) * 64 + kk + fk);
#pragma unroll
      for (int m = 0; m < 4; m++)
#pragma unroll
        for (int n = 0; n < 4; n++)
          acc[m][n] = __builtin_amdgcn_mfma_f32_16x16x32_bf16(av[m], bv[n], acc[m][n], 0, 0, 0);
    }
    __syncthreads();
  }
  const int rb = row0 + wm * 64 + ((lane >> 4) << 2);
  const int cb = tn * 128 + wn * 64 + fr;
#pragma unroll
  for (int m = 0; m < 4; m++)
#pragma unroll
    for (int i = 0; i < 4; i++) {
      int r = rb + m * 16 + i;
      float* dst = ybuf + (size_t)r * HD + cb;
#pragma unroll
      for (int n = 0; n < 4; n++) dst[n * 16] = acc[m][n][i];
    }
}

// ---------------- combine: out[t] = w0*y[slot0] + w1*y[slot1] ----------------
__global__ __launch_bounds__(256) void combine_kernel(
    const float* __restrict__ ybuf, const int* __restrict__ slots,
    const float* __restrict__ tw, float* __restrict__ out) {
  int t = blockIdx.x * 4 + (threadIdx.x >> 6);
  int lane = threadIdx.x & 63;
  int r0 = slots[t * 2 + 0], r1 = slots[t * 2 + 1];
  float w0 = tw[t * 2 + 0], w1 = tw[t * 2 + 1];
  const float4* y0 = (const float4*)(ybuf + (size_t)r0 * HD);
  const float4* y1 = (const float4*)(ybuf + (size_t)r1 * HD);
  float4* o = (float4*)(out + (size_t)t * HD);
#pragma unroll
  for (int j = 0; j < 4; j++) {
    int ix = j * 64 + lane;
    float4 a = y0[ix], b = y1[ix];
    float4 c;
    c.x = w0 * a.x + w1 * b.x; c.y = w0 * a.y + w1 * b.y;
    c.z = w0 * a.z + w1 * b.z; c.w = w0 * a.w + w1 * b.w;
    o[ix] = c;
  }
}

extern "C" void kernel_launch(void* const* d_in, const int* in_sizes, int n_in,
                              void* d_out, int out_size, void* d_ws, size_t ws_size,
                              hipStream_t stream) {
  (void)in_sizes; (void)n_in; (void)out_size; (void)ws_size;
  const float* h  = (const float*)d_in[0];
  const float* rw = (const float*)d_in[1];
  const float* gw = (const float*)d_in[2];
  const float* uw = (const float*)d_in[3];
  const float* dw = (const float*)d_in[4];
  float* out = (float*)d_out;

  char* ws = (char*)d_ws;
  size_t off = 0;
  auto alloc = [&](size_t bytes) { char* p = ws + off; off += (bytes + 255) & ~255ULL; return p; };
  __hip_bfloat16* wg  = (__hip_bfloat16*)alloc((size_t)NE * ID * HD * 2);
  __hip_bfloat16* wu  = (__hip_bfloat16*)alloc((size_t)NE * ID * HD * 2);
  __hip_bfloat16* wd  = (__hip_bfloat16*)alloc((size_t)NE * HD * ID * 2);
  __hip_bfloat16* hx  = (__hip_bfloat16*)alloc((size_t)TOKENS * HD * 2);
  __hip_bfloat16* A1  = (__hip_bfloat16*)alloc((size_t)RMAX * HD * 2);
  __hip_bfloat16* act = (__hip_bfloat16*)alloc((size_t)RMAX * ID * 2);
  float* ybuf = (float*)alloc((size_t)RMAX * HD * 4);
  int* rowmap = (int*)alloc(RMAX * 4);
  int* tidx   = (int*)alloc(TOKENS * 2 * 4);
  float* twt  = (float*)alloc(TOKENS * 2 * 4);
  int* slots  = (int*)alloc(TOKENS * 2 * 4);
  int* cnt    = (int*)alloc(256);
  int* cnt2   = (int*)alloc(256);
  int* ofs    = (int*)alloc(256);

  hipMemsetAsync(cnt, 0, NE * 4, stream);
  hipMemsetAsync(rowmap, 0xFF, RMAX * 4, stream);

  convert_kernel<<<16384, 256, 0, stream>>>(gw, wg);
  convert_kernel<<<16384, 256, 0, stream>>>(uw, wu);
  convert_kernel<<<16384, 256, 0, stream>>>(dw, wd);
  router_kernel<<<TOKENS / 4, 256, 0, stream>>>(h, rw, hx, tidx, twt, cnt);
  scan_kernel<<<1, 64, 0, stream>>>(cnt, ofs, cnt2);
  scatter_kernel<<<TOKENS / 256, 256, 0, stream>>>(tidx, twt, ofs, cnt2, rowmap, slots);
  gather_kernel<<<RMAX / 4, 256, 0, stream>>>(hx, rowmap, ofs, A1);
  dim3 g1(MAXT, ID / 128);
  gemm1_kernel<<<g1, 256, 0, stream>>>(A1, wg, wu, ofs, act);
  dim3 g2(MAXT, HD / 128);
  gemm2_kernel<<<g2, 256, 0, stream>>>(act, wd, ofs, ybuf);
  combine_kernel<<<TOKENS / 4, 256, 0, stream>>>(ybuf, slots, twt, out);
}

// Round 2
// 925.387 us; speedup vs baseline: 1.1077x; 1.1077x over previous
//
#include <hip/hip_runtime.h>
#include <hip/hip_bf16.h>
#include <math.h>
#include <stdint.h>

// Problem constants (B=4, S=2048, H=1024, I=4096, E=8, K=2)
#define TOKENS 8192
#define HD 1024
#define ID 4096
#define NE 8
#define RMAX 18432   // 16384 + 8*256 worst-case padded rows (experts padded to 256)
#define MAXT 72      // RMAX/256 max M-tiles

typedef __attribute__((ext_vector_type(8))) short short8v;
typedef __attribute__((ext_vector_type(4))) float f32x4;

typedef const __attribute__((address_space(1))) unsigned int* gas_u32p;
typedef __attribute__((address_space(3))) unsigned int* las_u32p;

__device__ __forceinline__ void stage16(const void* g, void* l) {
  __builtin_amdgcn_global_load_lds((gas_u32p)g, (las_u32p)l, 16, 0, 0);
}

#define BARRIER asm volatile("s_barrier" ::: "memory")
#define WAITLGKM asm volatile("s_waitcnt lgkmcnt(0)" ::: "memory")
#define VMC0 asm volatile("s_waitcnt vmcnt(0)" ::: "memory")
#define VMC4 asm volatile("s_waitcnt vmcnt(4)" ::: "memory")
#define VMC6 asm volatile("s_waitcnt vmcnt(6)" ::: "memory")

// ---------------- weight fp32 -> bf16 convert ----------------
__global__ __launch_bounds__(256) void convert_kernel(const float* __restrict__ src,
                                                      __hip_bfloat16* __restrict__ dst) {
  size_t i = ((size_t)blockIdx.x * 256 + threadIdx.x) * 8;
  float4 a = ((const float4*)(src + i))[0];
  float4 b = ((const float4*)(src + i))[1];
  union { __hip_bfloat16 h[8]; int4 v; } u;
  u.h[0] = __float2bfloat16(a.x); u.h[1] = __float2bfloat16(a.y);
  u.h[2] = __float2bfloat16(a.z); u.h[3] = __float2bfloat16(a.w);
  u.h[4] = __float2bfloat16(b.x); u.h[5] = __float2bfloat16(b.y);
  u.h[6] = __float2bfloat16(b.z); u.h[7] = __float2bfloat16(b.w);
  *(int4*)(dst + i) = u.v;
}

// ---------------- router: logits (fp64 acc), top-2, weights; also h->bf16 ----------------
__global__ __launch_bounds__(256) void router_kernel(
    const float* __restrict__ h, const float* __restrict__ rw,
    __hip_bfloat16* __restrict__ hx, int* __restrict__ tidx,
    float* __restrict__ tw, int* __restrict__ cnt) {
  int wid = threadIdx.x >> 6, lane = threadIdx.x & 63;
  int t = blockIdx.x * 4 + wid;  // grid = TOKENS/4
  const float4* h4 = (const float4*)(h + (size_t)t * HD);
  float x[16];
  {
    float4 xa = h4[lane * 4 + 0], xb = h4[lane * 4 + 1], xc = h4[lane * 4 + 2], xd = h4[lane * 4 + 3];
    x[0] = xa.x; x[1] = xa.y; x[2] = xa.z; x[3] = xa.w;
    x[4] = xb.x; x[5] = xb.y; x[6] = xb.z; x[7] = xb.w;
    x[8] = xc.x; x[9] = xc.y; x[10] = xc.z; x[11] = xc.w;
    x[12] = xd.x; x[13] = xd.y; x[14] = xd.z; x[15] = xd.w;
  }
  union { __hip_bfloat16 hb[16]; int4 v[2]; } u;
#pragma unroll
  for (int j = 0; j < 16; j++) u.hb[j] = __float2bfloat16(x[j]);
  {
    int4* hxp = (int4*)(hx + (size_t)t * HD + lane * 16);
    hxp[0] = u.v[0]; hxp[1] = u.v[1];
  }
  double acc[NE];
#pragma unroll
  for (int e = 0; e < NE; e++) {
    const float4* w4 = (const float4*)(rw + e * HD);
    float4 wa = w4[lane * 4 + 0], wb = w4[lane * 4 + 1], wc = w4[lane * 4 + 2], wd = w4[lane * 4 + 3];
    double s = 0.0;
    s += (double)x[0] * wa.x + (double)x[1] * wa.y + (double)x[2] * wa.z + (double)x[3] * wa.w;
    s += (double)x[4] * wb.x + (double)x[5] * wb.y + (double)x[6] * wb.z + (double)x[7] * wb.w;
    s += (double)x[8] * wc.x + (double)x[9] * wc.y + (double)x[10] * wc.z + (double)x[11] * wc.w;
    s += (double)x[12] * wd.x + (double)x[13] * wd.y + (double)x[14] * wd.z + (double)x[15] * wd.w;
    acc[e] = s;
  }
#pragma unroll
  for (int off = 32; off >= 1; off >>= 1)
#pragma unroll
    for (int e = 0; e < NE; e++) acc[e] += __shfl_xor(acc[e], off, 64);
  if (lane == 0) {
    int i0 = 0; double l0 = acc[0];
#pragma unroll
    for (int e = 1; e < NE; e++) if (acc[e] > l0) { l0 = acc[e]; i0 = e; }
    int i1 = -1; double l1 = -1.0e300;
#pragma unroll
    for (int e = 0; e < NE; e++) if (e != i0 && acc[e] > l1) { l1 = acc[e]; i1 = e; }
    double r = exp(l1 - l0);  // <= 1
    float w0 = (float)(1.0 / (1.0 + r));
    float w1 = (float)(r / (1.0 + r));
    tidx[t * 2 + 0] = i0; tidx[t * 2 + 1] = i1;
    tw[t * 2 + 0] = w0;  tw[t * 2 + 1] = w1;
    atomicAdd(&cnt[i0], 1); atomicAdd(&cnt[i1], 1);
  }
}

// ---------------- offsets scan (pad each expert to 256 rows) ----------------
__global__ void scan_kernel(const int* __restrict__ cnt, int* __restrict__ ofs, int* __restrict__ cnt2) {
  if (threadIdx.x == 0) {
    int a = 0;
    for (int e = 0; e < NE; e++) { ofs[e] = a; a += (cnt[e] + 255) & ~255; }
    ofs[NE] = a;
  }
  if (threadIdx.x < NE) cnt2[threadIdx.x] = 0;
}

// ---------------- scatter token -> expert row lists ----------------
__global__ __launch_bounds__(256) void scatter_kernel(
    const int* __restrict__ tidx, const float* __restrict__ tw,
    const int* __restrict__ ofs, int* __restrict__ cnt2,
    int* __restrict__ rowmap, int* __restrict__ slots) {
  int t = blockIdx.x * 256 + threadIdx.x;  // grid = TOKENS/256
#pragma unroll
  for (int k = 0; k < 2; k++) {
    int e = tidx[t * 2 + k];
    int pos = atomicAdd(&cnt2[e], 1);
    int row = ofs[e] + pos;
    rowmap[row] = t;
    slots[t * 2 + k] = row;
  }
}

// ---------------- gather bf16 hidden rows into compacted A1 (zero pad rows) ----------------
__global__ __launch_bounds__(256) void gather_kernel(
    const __hip_bfloat16* __restrict__ hx, const int* __restrict__ rowmap,
    const int* __restrict__ ofs, __hip_bfloat16* __restrict__ A1) {
  int r = blockIdx.x * 4 + (threadIdx.x >> 6);
  int lane = threadIdx.x & 63;
  if (r >= ofs[NE]) return;
  int t = rowmap[r];
  int4* dst = (int4*)(A1 + (size_t)r * HD);
  if (t < 0) {
    int4 z = {0, 0, 0, 0};
    dst[lane * 2 + 0] = z; dst[lane * 2 + 1] = z;
  } else {
    const int4* src = (const int4*)(hx + (size_t)t * HD);
    dst[lane * 2 + 0] = src[lane * 2 + 0];
    dst[lane * 2 + 1] = src[lane * 2 + 1];
  }
}

// MFMA quadrant: 4 m-frags x 2 n-frags x 2 kk = 16 MFMA
#define MFMAQ(ACC, MO, NO, AF, BF)                                                         \
  { _Pragma("unroll") for (int m_ = 0; m_ < 4; m_++)                                       \
    _Pragma("unroll") for (int n_ = 0; n_ < 2; n_++)                                       \
    _Pragma("unroll") for (int k_ = 0; k_ < 2; k_++)                                       \
      ACC[(MO) + m_][(NO) + n_] = __builtin_amdgcn_mfma_f32_16x16x32_bf16(                 \
          AF[m_][k_], BF[n_][k_], ACC[(MO) + m_][(NO) + n_], 0, 0, 0); }

// =================== GEMM1 (fused gate+up+silu), 256x128 tile, 8-phase ===================
// LDS: per buffer 64KB: A[256x64] @0, G[128x64] @32768, U[128x64] @49152; x2 buffers.
__global__ __launch_bounds__(512, 2) void gemm1_kernel(
    const __hip_bfloat16* __restrict__ A1, const __hip_bfloat16* __restrict__ Wg,
    const __hip_bfloat16* __restrict__ Wu, const int* __restrict__ ofs,
    __hip_bfloat16* __restrict__ act) {
  __shared__ __align__(128) char lds[131072];
  const int nwg = gridDim.x;              // 2304 (div by 8)
  int wg0 = blockIdx.x;
  int wg = (wg0 & 7) * (nwg >> 3) + (wg0 >> 3);  // XCD-chunked swizzle
  const int tm = wg >> 5, tn = wg & 31;   // NTN = 32
  const int Rtot = ofs[NE];
  const int row0 = tm * 256;
  if (row0 >= Rtot) return;
  int e = 0;
#pragma unroll
  for (int i = 1; i < NE; i++) e += (row0 >= ofs[i]);
  const int tid = threadIdx.x, wid = tid >> 6, lane = tid & 63;
  const int wm = wid >> 1, wn = wid & 1;  // 4 M-warps x 2 N-warps
  const int fr = lane & 15, fkE = (lane >> 4) << 3;
  const int wmB = wm * 64, wnB = wn * 64;

  // stage source addresses (pre-swizzled global so linear global_load_lds dest = swizzled layout)
  const char* srcA[4]; const char* srcG[2]; const char* srcU[2];
  int ldA[4], ldG[2], ldU[2];
#pragma unroll
  for (int j = 0; j < 4; j++) {
    int d = j * 8192 + tid * 16;
    int row = d >> 7;
    int kb = (d ^ (((d >> 7) & 7) << 4)) & 127;
    srcA[j] = (const char*)(A1 + (size_t)(row0 + row) * HD) + kb;
    ldA[j] = j * 8192 + wid * 1024;
  }
#pragma unroll
  for (int j = 0; j < 2; j++) {
    int d = j * 8192 + tid * 16;
    int row = d >> 7;
    int kb = (d ^ (((d >> 7) & 7) << 4)) & 127;
    srcG[j] = (const char*)(Wg + ((size_t)e * ID + tn * 128 + row) * HD) + kb;
    srcU[j] = (const char*)(Wu + ((size_t)e * ID + tn * 128 + row) * HD) + kb;
    ldG[j] = 32768 + j * 8192 + wid * 1024;
    ldU[j] = 49152 + j * 8192 + wid * 1024;
  }
#define STG_A(j, t, bf) stage16(srcA[j] + (size_t)(t) * 128, (char*)lds + (bf) * 65536 + ldA[j])
#define STG_G(j, t, bf) stage16(srcG[j] + (size_t)(t) * 128, (char*)lds + (bf) * 65536 + ldG[j])
#define STG_U(j, t, bf) stage16(srcU[j] + (size_t)(t) * 128, (char*)lds + (bf) * 65536 + ldU[j])

  auto RD = [&](int bf, int poff, int rowi, int kki) -> short8v {
    int o = ((rowi + fr) << 7) + ((kki << 5) + fkE) * 2;
    o ^= ((o >> 7) & 7) << 4;  // st swizzle (matches staged layout)
    return *(const short8v*)(&lds[bf * 65536 + poff + o]);
  };

  f32x4 accG[4][4], accU[4][4];
#pragma unroll
  for (int m = 0; m < 4; m++)
#pragma unroll
    for (int n = 0; n < 4; n++) { accG[m][n] = (f32x4)(0.0f); accU[m][n] = (f32x4)(0.0f); }

  const int NT = HD / 64;  // 16 K-tiles
  // prologue: A(0),G(0),U(0) -> buf0; A(1),G(1) -> buf1  (14 loads)
#pragma unroll
  for (int j = 0; j < 4; j++) STG_A(j, 0, 0);
#pragma unroll
  for (int j = 0; j < 2; j++) STG_G(j, 0, 0);
#pragma unroll
  for (int j = 0; j < 2; j++) STG_U(j, 0, 0);
#pragma unroll
  for (int j = 0; j < 4; j++) STG_A(j, 1, 1);
#pragma unroll
  for (int j = 0; j < 2; j++) STG_G(j, 1, 1);
  VMC6; BARRIER;

#pragma unroll 1
  for (int I = 0; I < NT / 2; ++I) {
    const int t0 = 2 * I;
    const bool more = (t0 + 2 < NT);
    short8v a[4][2], bA[2][2], bB[2][2];
    // ---- P1: tile t0/buf0: read A(all)+G(n0-1); stage U(t0+1)->buf1 ----
#pragma unroll
    for (int m = 0; m < 4; m++) { a[m][0] = RD(0, 0, wmB + m * 16, 0); a[m][1] = RD(0, 0, wmB + m * 16, 1); }
#pragma unroll
    for (int n = 0; n < 2; n++) { bA[n][0] = RD(0, 32768, wnB + n * 16, 0); bA[n][1] = RD(0, 32768, wnB + n * 16, 1); }
    STG_U(0, t0 + 1, 1); STG_U(1, t0 + 1, 1);
    BARRIER; WAITLGKM;
    __builtin_amdgcn_s_setprio(1); MFMAQ(accG, 0, 0, a, bA); __builtin_amdgcn_s_setprio(0);
    BARRIER;
    // ---- P2: read G(n2-3); stage A(t0+2) 0,1 -> buf0 ----
#pragma unroll
    for (int n = 0; n < 2; n++) { bB[n][0] = RD(0, 32768, wnB + 32 + n * 16, 0); bB[n][1] = RD(0, 32768, wnB + 32 + n * 16, 1); }
    if (more) { STG_A(0, t0 + 2, 0); STG_A(1, t0 + 2, 0); }
    BARRIER; WAITLGKM;
    __builtin_amdgcn_s_setprio(1); MFMAQ(accG, 0, 2, a, bB); __builtin_amdgcn_s_setprio(0);
    BARRIER;
    // ---- P3: read U(n0-1); stage A(t0+2) 2,3 ----
#pragma unroll
    for (int n = 0; n < 2; n++) { bA[n][0] = RD(0, 49152, wnB + n * 16, 0); bA[n][1] = RD(0, 49152, wnB + n * 16, 1); }
    if (more) { STG_A(2, t0 + 2, 0); STG_A(3, t0 + 2, 0); }
    BARRIER; WAITLGKM;
    __builtin_amdgcn_s_setprio(1); MFMAQ(accU, 0, 0, a, bA); __builtin_amdgcn_s_setprio(0);
    BARRIER;
    // ---- P4: read U(n2-3); stage G(t0+2); vmcnt; barrier ----
#pragma unroll
    for (int n = 0; n < 2; n++) { bB[n][0] = RD(0, 49152, wnB + 32 + n * 16, 0); bB[n][1] = RD(0, 49152, wnB + 32 + n * 16, 1); }
    if (more) { STG_G(0, t0 + 2, 0); STG_G(1, t0 + 2, 0); }
    BARRIER; WAITLGKM;
    __builtin_amdgcn_s_setprio(1); MFMAQ(accU, 0, 2, a, bB); __builtin_amdgcn_s_setprio(0);
    if (more) { VMC6; } else { VMC0; }
    BARRIER;
    // ---- P5: tile t0+1/buf1: read A(all)+G(n0-1); stage U(t0+2)->buf0 ----
#pragma unroll
    for (int m = 0; m < 4; m++) { a[m][0] = RD(1, 0, wmB + m * 16, 0); a[m][1] = RD(1, 0, wmB + m * 16, 1); }
#pragma unroll
    for (int n = 0; n < 2; n++) { bA[n][0] = RD(1, 32768, wnB + n * 16, 0); bA[n][1] = RD(1, 32768, wnB + n * 16, 1); }
    if (more) { STG_U(0, t0 + 2, 0); STG_U(1, t0 + 2, 0); }
    BARRIER; WAITLGKM;
    __builtin_amdgcn_s_setprio(1); MFMAQ(accG, 0, 0, a, bA); __builtin_amdgcn_s_setprio(0);
    BARRIER;
    // ---- P6: read G(n2-3); stage A(t0+3) 0,1 -> buf1 ----
#pragma unroll
    for (int n = 0; n < 2; n++) { bB[n][0] = RD(1, 32768, wnB + 32 + n * 16, 0); bB[n][1] = RD(1, 32768, wnB + 32 + n * 16, 1); }
    if (more) { STG_A(0, t0 + 3, 1); STG_A(1, t0 + 3, 1); }
    BARRIER; WAITLGKM;
    __builtin_amdgcn_s_setprio(1); MFMAQ(accG, 0, 2, a, bB); __builtin_amdgcn_s_setprio(0);
    BARRIER;
    // ---- P7: read U(n0-1); stage A(t0+3) 2,3 ----
#pragma unroll
    for (int n = 0; n < 2; n++) { bA[n][0] = RD(1, 49152, wnB + n * 16, 0); bA[n][1] = RD(1, 49152, wnB + n * 16, 1); }
    if (more) { STG_A(2, t0 + 3, 1); STG_A(3, t0 + 3, 1); }
    BARRIER; WAITLGKM;
    __builtin_amdgcn_s_setprio(1); MFMAQ(accU, 0, 0, a, bA); __builtin_amdgcn_s_setprio(0);
    BARRIER;
    // ---- P8: read U(n2-3); stage G(t0+3); vmcnt; barrier ----
#pragma unroll
    for (int n = 0; n < 2; n++) { bB[n][0] = RD(1, 49152, wnB + 32 + n * 16, 0); bB[n][1] = RD(1, 49152, wnB + 32 + n * 16, 1); }
    if (more) { STG_G(0, t0 + 3, 1); STG_G(1, t0 + 3, 1); }
    BARRIER; WAITLGKM;
    __builtin_amdgcn_s_setprio(1); MFMAQ(accU, 0, 2, a, bB); __builtin_amdgcn_s_setprio(0);
    if (more) { VMC6; } else { VMC0; }
    BARRIER;
  }
#undef STG_A
#undef STG_G
#undef STG_U

  // epilogue: act = bf16(silu(g) * u). C layout: col=lane&15, row=(lane>>4)*4+i.
  const int rb = row0 + wmB + ((lane >> 4) << 2);
  const int cb = tn * 128 + wnB + fr;
#pragma unroll
  for (int m = 0; m < 4; m++)
#pragma unroll
    for (int i = 0; i < 4; i++) {
      int r = rb + m * 16 + i;
      __hip_bfloat16* dst = act + (size_t)r * ID + cb;
#pragma unroll
      for (int n = 0; n < 4; n++) {
        float g = accG[m][n][i], uu = accU[m][n][i];
        float s = g / (1.0f + __expf(-g));
        dst[n * 16] = __float2bfloat16(s * uu);
      }
    }
}

// =================== GEMM2: y = act @ Wd[e]^T, 256x256 tile, 8-phase ===================
// LDS: per buffer 64KB: A[256x64] @0, B[256x64] @32768; x2 buffers.
__global__ __launch_bounds__(512, 2) void gemm2_kernel(
    const __hip_bfloat16* __restrict__ act, const __hip_bfloat16* __restrict__ Wd,
    const int* __restrict__ ofs, float* __restrict__ ybuf) {
  __shared__ __align__(128) char lds[131072];
  const int nwg = gridDim.x;              // 288 (div by 8)
  int wg0 = blockIdx.x;
  int wg = (wg0 & 7) * (nwg >> 3) + (wg0 >> 3);
  const int tm = wg >> 2, tn = wg & 3;    // NTN = 4
  const int Rtot = ofs[NE];
  const int row0 = tm * 256;
  if (row0 >= Rtot) return;
  int e = 0;
#pragma unroll
  for (int i = 1; i < NE; i++) e += (row0 >= ofs[i]);
  const int tid = threadIdx.x, wid = tid >> 6, lane = tid & 63;
  const int wm = wid >> 2, wn = wid & 3;  // 2 M-warps x 4 N-warps
  const int fr = lane & 15, fkE = (lane >> 4) << 3;
  const int wmB = wm * 128, wnB = wn * 64;

  const char* srcA[4]; const char* srcB[4];
  int ldA[4], ldB[4];
#pragma unroll
  for (int j = 0; j < 4; j++) {
    int d = j * 8192 + tid * 16;
    int row = d >> 7;
    int kb = (d ^ (((d >> 7) & 7) << 4)) & 127;
    srcA[j] = (const char*)(act + (size_t)(row0 + row) * ID) + kb;
    srcB[j] = (const char*)(Wd + ((size_t)e * HD + tn * 256 + row) * ID) + kb;
    ldA[j] = j * 8192 + wid * 1024;
    ldB[j] = 32768 + j * 8192 + wid * 1024;
  }
#define STG_A2(j, t, bf) stage16(srcA[j] + (size_t)(t) * 128, (char*)lds + (bf) * 65536 + ldA[j])
#define STG_B2(j, t, bf) stage16(srcB[j] + (size_t)(t) * 128, (char*)lds + (bf) * 65536 + ldB[j])

  auto RD = [&](int bf, int poff, int rowi, int kki) -> short8v {
    int o = ((rowi + fr) << 7) + ((kki << 5) + fkE) * 2;
    o ^= ((o >> 7) & 7) << 4;
    return *(const short8v*)(&lds[bf * 65536 + poff + o]);
  };

  f32x4 acc[8][4];
#pragma unroll
  for (int m = 0; m < 8; m++)
#pragma unroll
    for (int n = 0; n < 4; n++) acc[m][n] = (f32x4)(0.0f);

  const int NT = ID / 64;  // 64 K-tiles
  // prologue: B(0)->buf0, A(0)->buf0, B(1)->buf1  (12 loads)
#pragma unroll
  for (int j = 0; j < 4; j++) STG_B2(j, 0, 0);
#pragma unroll
  for (int j = 0; j < 4; j++) STG_A2(j, 0, 0);
#pragma unroll
  for (int j = 0; j < 4; j++) STG_B2(j, 1, 1);
  VMC4; BARRIER;

#pragma unroll 1
  for (int I = 0; I < NT / 2; ++I) {
    const int t0 = 2 * I;
    const bool more = (t0 + 2 < NT);
    short8v a0[4][2], a1[4][2], b0[2][2], b1[2][2];
    // ---- P1: tile t0/buf0: read A(m0-3)+B(n0-1); stage A(t0+1) 0,1 -> buf1 ----
#pragma unroll
    for (int m = 0; m < 4; m++) { a0[m][0] = RD(0, 0, wmB + m * 16, 0); a0[m][1] = RD(0, 0, wmB + m * 16, 1); }
#pragma unroll
    for (int n = 0; n < 2; n++) { b0[n][0] = RD(0, 32768, wnB + n * 16, 0); b0[n][1] = RD(0, 32768, wnB + n * 16, 1); }
    STG_A2(0, t0 + 1, 1); STG_A2(1, t0 + 1, 1);
    BARRIER; WAITLGKM;
    __builtin_amdgcn_s_setprio(1); MFMAQ(acc, 0, 0, a0, b0); __builtin_amdgcn_s_setprio(0);
    BARRIER;
    // ---- P2: read B(n2-3); stage A(t0+1) 2,3 ----
#pragma unroll
    for (int n = 0; n < 2; n++) { b1[n][0] = RD(0, 32768, wnB + 32 + n * 16, 0); b1[n][1] = RD(0, 32768, wnB + 32 + n * 16, 1); }
    STG_A2(2, t0 + 1, 1); STG_A2(3, t0 + 1, 1);
    BARRIER; WAITLGKM;
    __builtin_amdgcn_s_setprio(1); MFMAQ(acc, 0, 2, a0, b1); __builtin_amdgcn_s_setprio(0);
    BARRIER;
    // ---- P3: read A(m4-7); stage B(t0+2) 0,1 -> buf0 ----
#pragma unroll
    for (int m = 0; m < 4; m++) { a1[m][0] = RD(0, 0, wmB + 64 + m * 16, 0); a1[m][1] = RD(0, 0, wmB + 64 + m * 16, 1); }
    if (more) { STG_B2(0, t0 + 2, 0); STG_B2(1, t0 + 2, 0); }
    BARRIER; WAITLGKM;
    __builtin_amdgcn_s_setprio(1); MFMAQ(acc, 4, 2, a1, b1); __builtin_amdgcn_s_setprio(0);
    BARRIER;
    // ---- P4: stage B(t0+2) 2,3; MFMA Q10; vmcnt; barrier ----
    if (more) { STG_B2(2, t0 + 2, 0); STG_B2(3, t0 + 2, 0); }
    BARRIER; WAITLGKM;
    __builtin_amdgcn_s_setprio(1); MFMAQ(acc, 4, 0, a1, b0); __builtin_amdgcn_s_setprio(0);
    if (more) { VMC4; } else { VMC0; }
    BARRIER;
    // ---- P5: tile t0+1/buf1: read A(m0-3)+B(n0-1); stage A(t0+2) 0,1 -> buf0 ----
#pragma unroll
    for (int m = 0; m < 4; m++) { a0[m][0] = RD(1, 0, wmB + m * 16, 0); a0[m][1] = RD(1, 0, wmB + m * 16, 1); }
#pragma unroll
    for (int n = 0; n < 2; n++) { b0[n][0] = RD(1, 32768, wnB + n * 16, 0); b0[n][1] = RD(1, 32768, wnB + n * 16, 1); }
    if (more) { STG_A2(0, t0 + 2, 0); STG_A2(1, t0 + 2, 0); }
    BARRIER; WAITLGKM;
    __builtin_amdgcn_s_setprio(1); MFMAQ(acc, 0, 0, a0, b0); __builtin_amdgcn_s_setprio(0);
    BARRIER;
    // ---- P6: read B(n2-3); stage A(t0+2) 2,3 ----
#pragma unroll
    for (int n = 0; n < 2; n++) { b1[n][0] = RD(1, 32768, wnB + 32 + n * 16, 0); b1[n][1] = RD(1, 32768, wnB + 32 + n * 16, 1); }
    if (more) { STG_A2(2, t0 + 2, 0); STG_A2(3, t0 + 2, 0); }
    BARRIER; WAITLGKM;
    __builtin_amdgcn_s_setprio(1); MFMAQ(acc, 0, 2, a0, b1); __builtin_amdgcn_s_setprio(0);
    BARRIER;
    // ---- P7: read A(m4-7); stage B(t0+3) 0,1 -> buf1 ----
#pragma unroll
    for (int m = 0; m < 4; m++) { a1[m][0] = RD(1, 0, wmB + 64 + m * 16, 0); a1[m][1] = RD(1, 0, wmB + 64 + m * 16, 1); }
    if (more) { STG_B2(0, t0 + 3, 1); STG_B2(1, t0 + 3, 1); }
    BARRIER; WAITLGKM;
    __builtin_amdgcn_s_setprio(1); MFMAQ(acc, 4, 2, a1, b1); __builtin_amdgcn_s_setprio(0);
    BARRIER;
    // ---- P8: stage B(t0+3) 2,3; MFMA Q10; vmcnt; barrier ----
    if (more) { STG_B2(2, t0 + 3, 1); STG_B2(3, t0 + 3, 1); }
    BARRIER; WAITLGKM;
    __builtin_amdgcn_s_setprio(1); MFMAQ(acc, 4, 0, a1, b0); __builtin_amdgcn_s_setprio(0);
    if (more) { VMC4; } else { VMC0; }
    BARRIER;
  }
#undef STG_A2
#undef STG_B2

  const int rb = row0 + wmB + ((lane >> 4) << 2);
  const int cb = tn * 256 + wnB + fr;
#pragma unroll
  for (int m = 0; m < 8; m++)
#pragma unroll
    for (int i = 0; i < 4; i++) {
      int r = rb + m * 16 + i;
      float* dst = ybuf + (size_t)r * HD + cb;
#pragma unroll
      for (int n = 0; n < 4; n++) dst[n * 16] = acc[m][n][i];
    }
}

// ---------------- combine: out[t] = w0*y[slot0] + w1*y[slot1] ----------------
__global__ __launch_bounds__(256) void combine_kernel(
    const float* __restrict__ ybuf, const int* __restrict__ slots,
    const float* __restrict__ tw, float* __restrict__ out) {
  int t = blockIdx.x * 4 + (threadIdx.x >> 6);
  int lane = threadIdx.x & 63;
  int r0 = slots[t * 2 + 0], r1 = slots[t * 2 + 1];
  float w0 = tw[t * 2 + 0], w1 = tw[t * 2 + 1];
  const float4* y0 = (const float4*)(ybuf + (size_t)r0 * HD);
  const float4* y1 = (const float4*)(ybuf + (size_t)r1 * HD);
  float4* o = (float4*)(out + (size_t)t * HD);
#pragma unroll
  for (int j = 0; j < 4; j++) {
    int ix = j * 64 + lane;
    float4 a = y0[ix], b = y1[ix];
    float4 c;
    c.x = w0 * a.x + w1 * b.x; c.y = w0 * a.y + w1 * b.y;
    c.z = w0 * a.z + w1 * b.z; c.w = w0 * a.w + w1 * b.w;
    o[ix] = c;
  }
}

extern "C" void kernel_launch(void* const* d_in, const int* in_sizes, int n_in,
                              void* d_out, int out_size, void* d_ws, size_t ws_size,
                              hipStream_t stream) {
  (void)in_sizes; (void)n_in; (void)out_size; (void)ws_size;
  const float* h  = (const float*)d_in[0];
  const float* rw = (const float*)d_in[1];
  const float* gw = (const float*)d_in[2];
  const float* uw = (const float*)d_in[3];
  const float* dw = (const float*)d_in[4];
  float* out = (float*)d_out;

  char* ws = (char*)d_ws;
  size_t off = 0;
  auto alloc = [&](size_t bytes) { char* p = ws + off; off += (bytes + 255) & ~255ULL; return p; };
  __hip_bfloat16* wg  = (__hip_bfloat16*)alloc((size_t)NE * ID * HD * 2);
  __hip_bfloat16* wu  = (__hip_bfloat16*)alloc((size_t)NE * ID * HD * 2);
  __hip_bfloat16* wd  = (__hip_bfloat16*)alloc((size_t)NE * HD * ID * 2);
  __hip_bfloat16* act = (__hip_bfloat16*)alloc((size_t)RMAX * ID * 2);
  size_t hx_off = off;
  __hip_bfloat16* hx  = (__hip_bfloat16*)alloc((size_t)TOKENS * HD * 2);
  __hip_bfloat16* A1  = (__hip_bfloat16*)alloc((size_t)RMAX * HD * 2);
  // ybuf overlays hx+A1 (both dead once gemm2 runs); extend past A1 as needed
  float* ybuf = (float*)(ws + hx_off);
  {
    size_t yend = hx_off + (size_t)RMAX * HD * 4;
    if (yend > off) off = (yend + 255) & ~255ULL;
  }
  int* rowmap = (int*)alloc(RMAX * 4);
  int* tidx   = (int*)alloc(TOKENS * 2 * 4);
  float* twt  = (float*)alloc(TOKENS * 2 * 4);
  int* slots  = (int*)alloc(TOKENS * 2 * 4);
  int* cnt    = (int*)alloc(256);
  int* cnt2   = (int*)alloc(256);
  int* ofs    = (int*)alloc(256);

  hipMemsetAsync(cnt, 0, NE * 4, stream);
  hipMemsetAsync(rowmap, 0xFF, RMAX * 4, stream);

  convert_kernel<<<16384, 256, 0, stream>>>(gw, wg);
  convert_kernel<<<16384, 256, 0, stream>>>(uw, wu);
  convert_kernel<<<16384, 256, 0, stream>>>(dw, wd);
  router_kernel<<<TOKENS / 4, 256, 0, stream>>>(h, rw, hx, tidx, twt, cnt);
  scan_kernel<<<1, 64, 0, stream>>>(cnt, ofs, cnt2);
  scatter_kernel<<<TOKENS / 256, 256, 0, stream>>>(tidx, twt, ofs, cnt2, rowmap, slots);
  gather_kernel<<<RMAX / 4, 256, 0, stream>>>(hx, rowmap, ofs, A1);
  gemm1_kernel<<<MAXT * 32, 512, 0, stream>>>(A1, wg, wu, ofs, act);
  gemm2_kernel<<<MAXT * 4, 512, 0, stream>>>(act, wd, ofs, ybuf);
  combine_kernel<<<TOKENS / 4, 256, 0, stream>>>(ybuf, slots, twt, out);
}

// Round 3
// 898.111 us; speedup vs baseline: 1.1413x; 1.0304x over previous
//
#include <hip/hip_runtime.h>
#include <hip/hip_bf16.h>
#include <math.h>
#include <stdint.h>

// Problem constants (B=4, S=2048, H=1024, I=4096, E=8, K=2)
#define TOKENS 8192
#define HD 1024
#define ID 4096
#define NE 8
#define RMAX 18432   // 16384 + 8*256 worst-case padded rows (experts padded to 256)
#define MAXT 72      // RMAX/256 max M-tiles

typedef __attribute__((ext_vector_type(8))) short short8v;
typedef __attribute__((ext_vector_type(4))) float f32x4;

typedef const __attribute__((address_space(1))) unsigned int* gas_u32p;
typedef __attribute__((address_space(3))) unsigned int* las_u32p;

__device__ __forceinline__ void stage16(const void* g, void* l) {
  __builtin_amdgcn_global_load_lds((gas_u32p)g, (las_u32p)l, 16, 0, 0);
}

#define BARRIER asm volatile("s_barrier" ::: "memory")
#define WAITLGKM asm volatile("s_waitcnt lgkmcnt(0)" ::: "memory")
#define VMC0 asm volatile("s_waitcnt vmcnt(0)" ::: "memory")
#define VMC3 asm volatile("s_waitcnt vmcnt(3)" ::: "memory")
#define VMC6 asm volatile("s_waitcnt vmcnt(6)" ::: "memory")

// ---------------- weight fp32 -> bf16 convert ----------------
__global__ __launch_bounds__(256) void convert_kernel(const float* __restrict__ src,
                                                      __hip_bfloat16* __restrict__ dst) {
  size_t i = ((size_t)blockIdx.x * 256 + threadIdx.x) * 8;
  float4 a = ((const float4*)(src + i))[0];
  float4 b = ((const float4*)(src + i))[1];
  union { __hip_bfloat16 h[8]; int4 v; } u;
  u.h[0] = __float2bfloat16(a.x); u.h[1] = __float2bfloat16(a.y);
  u.h[2] = __float2bfloat16(a.z); u.h[3] = __float2bfloat16(a.w);
  u.h[4] = __float2bfloat16(b.x); u.h[5] = __float2bfloat16(b.y);
  u.h[6] = __float2bfloat16(b.z); u.h[7] = __float2bfloat16(b.w);
  *(int4*)(dst + i) = u.v;
}

// ---------------- router: logits (fp64 acc), top-2, weights; also h->bf16 ----------------
__global__ __launch_bounds__(256) void router_kernel(
    const float* __restrict__ h, const float* __restrict__ rw,
    __hip_bfloat16* __restrict__ hx, int* __restrict__ tidx,
    float* __restrict__ tw, int* __restrict__ cnt) {
  int wid = threadIdx.x >> 6, lane = threadIdx.x & 63;
  int t = blockIdx.x * 4 + wid;  // grid = TOKENS/4
  const float4* h4 = (const float4*)(h + (size_t)t * HD);
  float x[16];
  {
    float4 xa = h4[lane * 4 + 0], xb = h4[lane * 4 + 1], xc = h4[lane * 4 + 2], xd = h4[lane * 4 + 3];
    x[0] = xa.x; x[1] = xa.y; x[2] = xa.z; x[3] = xa.w;
    x[4] = xb.x; x[5] = xb.y; x[6] = xb.z; x[7] = xb.w;
    x[8] = xc.x; x[9] = xc.y; x[10] = xc.z; x[11] = xc.w;
    x[12] = xd.x; x[13] = xd.y; x[14] = xd.z; x[15] = xd.w;
  }
  union { __hip_bfloat16 hb[16]; int4 v[2]; } u;
#pragma unroll
  for (int j = 0; j < 16; j++) u.hb[j] = __float2bfloat16(x[j]);
  {
    int4* hxp = (int4*)(hx + (size_t)t * HD + lane * 16);
    hxp[0] = u.v[0]; hxp[1] = u.v[1];
  }
  double acc[NE];
#pragma unroll
  for (int e = 0; e < NE; e++) {
    const float4* w4 = (const float4*)(rw + e * HD);
    float4 wa = w4[lane * 4 + 0], wb = w4[lane * 4 + 1], wc = w4[lane * 4 + 2], wd = w4[lane * 4 + 3];
    double s = 0.0;
    s += (double)x[0] * wa.x + (double)x[1] * wa.y + (double)x[2] * wa.z + (double)x[3] * wa.w;
    s += (double)x[4] * wb.x + (double)x[5] * wb.y + (double)x[6] * wb.z + (double)x[7] * wb.w;
    s += (double)x[8] * wc.x + (double)x[9] * wc.y + (double)x[10] * wc.z + (double)x[11] * wc.w;
    s += (double)x[12] * wd.x + (double)x[13] * wd.y + (double)x[14] * wd.z + (double)x[15] * wd.w;
    acc[e] = s;
  }
#pragma unroll
  for (int off = 32; off >= 1; off >>= 1)
#pragma unroll
    for (int e = 0; e < NE; e++) acc[e] += __shfl_xor(acc[e], off, 64);
  if (lane == 0) {
    int i0 = 0; double l0 = acc[0];
#pragma unroll
    for (int e = 1; e < NE; e++) if (acc[e] > l0) { l0 = acc[e]; i0 = e; }
    int i1 = -1; double l1 = -1.0e300;
#pragma unroll
    for (int e = 0; e < NE; e++) if (e != i0 && acc[e] > l1) { l1 = acc[e]; i1 = e; }
    double r = exp(l1 - l0);  // <= 1
    float w0 = (float)(1.0 / (1.0 + r));
    float w1 = (float)(r / (1.0 + r));
    tidx[t * 2 + 0] = i0; tidx[t * 2 + 1] = i1;
    tw[t * 2 + 0] = w0;  tw[t * 2 + 1] = w1;
    atomicAdd(&cnt[i0], 1); atomicAdd(&cnt[i1], 1);
  }
}

// ---------------- offsets scan (pad each expert to 256 rows) ----------------
__global__ void scan_kernel(const int* __restrict__ cnt, int* __restrict__ ofs, int* __restrict__ cnt2) {
  if (threadIdx.x == 0) {
    int a = 0;
    for (int e = 0; e < NE; e++) { ofs[e] = a; a += (cnt[e] + 255) & ~255; }
    ofs[NE] = a;
  }
  if (threadIdx.x < NE) cnt2[threadIdx.x] = 0;
}

// ---------------- scatter token -> expert row lists ----------------
__global__ __launch_bounds__(256) void scatter_kernel(
    const int* __restrict__ tidx, const float* __restrict__ tw,
    const int* __restrict__ ofs, int* __restrict__ cnt2,
    int* __restrict__ rowmap, int* __restrict__ slots) {
  int t = blockIdx.x * 256 + threadIdx.x;  // grid = TOKENS/256
#pragma unroll
  for (int k = 0; k < 2; k++) {
    int e = tidx[t * 2 + k];
    int pos = atomicAdd(&cnt2[e], 1);
    int row = ofs[e] + pos;
    rowmap[row] = t;
    slots[t * 2 + k] = row;
  }
}

// MFMA quadrant: 4 m-frags x 2 n-frags x 2 kk = 16 MFMA
#define MFMAQ(ACC, MO, NO, AF, BF)                                                         \
  { _Pragma("unroll") for (int m_ = 0; m_ < 4; m_++)                                       \
    _Pragma("unroll") for (int n_ = 0; n_ < 2; n_++)                                       \
    _Pragma("unroll") for (int k_ = 0; k_ < 2; k_++)                                       \
      ACC[(MO) + m_][(NO) + n_] = __builtin_amdgcn_mfma_f32_16x16x32_bf16(                 \
          AF[m_][k_], BF[n_][k_], ACC[(MO) + m_][(NO) + n_], 0, 0, 0); }

// =================== GEMM1 (fused gate+up+silu), 256x128 tile, 8-phase ===================
// A-panel staged DIRECTLY from hx via rowmap (per-lane global source); pad rows read zrow.
// LDS: per buffer 64KB: A[256x64] @0, G[128x64] @32768, U[128x64] @49152; x2 buffers.
__global__ __launch_bounds__(512, 2) void gemm1_kernel(
    const __hip_bfloat16* __restrict__ hx, const __hip_bfloat16* __restrict__ Wg,
    const __hip_bfloat16* __restrict__ Wu, const int* __restrict__ rowmap,
    const int* __restrict__ ofs, const __hip_bfloat16* __restrict__ zrow,
    __hip_bfloat16* __restrict__ act) {
  __shared__ __align__(128) char lds[131072];
  const int nwg = gridDim.x;              // 2304 (div by 8)
  int wg0 = blockIdx.x;
  int wg = (wg0 & 7) * (nwg >> 3) + (wg0 >> 3);  // XCD-chunked swizzle
  const int tm = wg >> 5, tn = wg & 31;   // NTN = 32
  const int Rtot = ofs[NE];
  const int row0 = tm * 256;
  if (row0 >= Rtot) return;
  int e = 0;
#pragma unroll
  for (int i = 1; i < NE; i++) e += (row0 >= ofs[i]);
  const int tid = threadIdx.x, wid = tid >> 6, lane = tid & 63;
  const int wm = wid >> 1, wn = wid & 1;  // 4 M-warps x 2 N-warps
  const int fr = lane & 15, fkE = (lane >> 4) << 3;
  const int wmB = wm * 64, wnB = wn * 64;

  // stage source addresses (pre-swizzled global so linear global_load_lds dest = swizzled layout)
  const char* srcA[4]; const char* srcG[2]; const char* srcU[2];
  int ldA[4], ldG[2], ldU[2];
#pragma unroll
  for (int j = 0; j < 4; j++) {
    int d = j * 8192 + tid * 16;
    int row = d >> 7;
    int kb = (d ^ (((d >> 7) & 7) << 4)) & 127;
    int tok = rowmap[row0 + row];
    const __hip_bfloat16* base = (tok >= 0) ? (hx + (size_t)tok * HD) : zrow;
    srcA[j] = (const char*)base + kb;
    ldA[j] = j * 8192 + wid * 1024;
  }
#pragma unroll
  for (int j = 0; j < 2; j++) {
    int d = j * 8192 + tid * 16;
    int row = d >> 7;
    int kb = (d ^ (((d >> 7) & 7) << 4)) & 127;
    srcG[j] = (const char*)(Wg + ((size_t)e * ID + tn * 128 + row) * HD) + kb;
    srcU[j] = (const char*)(Wu + ((size_t)e * ID + tn * 128 + row) * HD) + kb;
    ldG[j] = 32768 + j * 8192 + wid * 1024;
    ldU[j] = 49152 + j * 8192 + wid * 1024;
  }
#define STG_A(j, t, bf) stage16(srcA[j] + (size_t)(t) * 128, (char*)lds + (bf) * 65536 + ldA[j])
#define STG_G(j, t, bf) stage16(srcG[j] + (size_t)(t) * 128, (char*)lds + (bf) * 65536 + ldG[j])
#define STG_U(j, t, bf) stage16(srcU[j] + (size_t)(t) * 128, (char*)lds + (bf) * 65536 + ldU[j])

  auto RD = [&](int bf, int poff, int rowi, int kki) -> short8v {
    int o = ((rowi + fr) << 7) + ((kki << 5) + fkE) * 2;
    o ^= ((o >> 7) & 7) << 4;  // st swizzle (matches staged layout)
    return *(const short8v*)(&lds[bf * 65536 + poff + o]);
  };

  f32x4 accG[4][4], accU[4][4];
#pragma unroll
  for (int m = 0; m < 4; m++)
#pragma unroll
    for (int n = 0; n < 4; n++) { accG[m][n] = (f32x4)(0.0f); accU[m][n] = (f32x4)(0.0f); }

  const int NT = HD / 64;  // 16 K-tiles
  // prologue: A(0),G(0),U(0) -> buf0; A(1),G(1) -> buf1  (14 loads)
#pragma unroll
  for (int j = 0; j < 4; j++) STG_A(j, 0, 0);
#pragma unroll
  for (int j = 0; j < 2; j++) STG_G(j, 0, 0);
#pragma unroll
  for (int j = 0; j < 2; j++) STG_U(j, 0, 0);
#pragma unroll
  for (int j = 0; j < 4; j++) STG_A(j, 1, 1);
#pragma unroll
  for (int j = 0; j < 2; j++) STG_G(j, 1, 1);
  VMC6; BARRIER;

#pragma unroll 1
  for (int I = 0; I < NT / 2; ++I) {
    const int t0 = 2 * I;
    const bool more = (t0 + 2 < NT);
    short8v a[4][2], bA[2][2], bB[2][2];
    // ---- P1: tile t0/buf0: read A(all)+G(n0-1); stage U(t0+1)->buf1 ----
#pragma unroll
    for (int m = 0; m < 4; m++) { a[m][0] = RD(0, 0, wmB + m * 16, 0); a[m][1] = RD(0, 0, wmB + m * 16, 1); }
#pragma unroll
    for (int n = 0; n < 2; n++) { bA[n][0] = RD(0, 32768, wnB + n * 16, 0); bA[n][1] = RD(0, 32768, wnB + n * 16, 1); }
    STG_U(0, t0 + 1, 1); STG_U(1, t0 + 1, 1);
    BARRIER; WAITLGKM;
    __builtin_amdgcn_s_setprio(1); MFMAQ(accG, 0, 0, a, bA); __builtin_amdgcn_s_setprio(0);
    BARRIER;
    // ---- P2: read G(n2-3); stage A(t0+2) 0,1 -> buf0 ----
#pragma unroll
    for (int n = 0; n < 2; n++) { bB[n][0] = RD(0, 32768, wnB + 32 + n * 16, 0); bB[n][1] = RD(0, 32768, wnB + 32 + n * 16, 1); }
    if (more) { STG_A(0, t0 + 2, 0); STG_A(1, t0 + 2, 0); }
    BARRIER; WAITLGKM;
    __builtin_amdgcn_s_setprio(1); MFMAQ(accG, 0, 2, a, bB); __builtin_amdgcn_s_setprio(0);
    BARRIER;
    // ---- P3: read U(n0-1); stage A(t0+2) 2,3 ----
#pragma unroll
    for (int n = 0; n < 2; n++) { bA[n][0] = RD(0, 49152, wnB + n * 16, 0); bA[n][1] = RD(0, 49152, wnB + n * 16, 1); }
    if (more) { STG_A(2, t0 + 2, 0); STG_A(3, t0 + 2, 0); }
    BARRIER; WAITLGKM;
    __builtin_amdgcn_s_setprio(1); MFMAQ(accU, 0, 0, a, bA); __builtin_amdgcn_s_setprio(0);
    BARRIER;
    // ---- P4: read U(n2-3); stage G(t0+2); vmcnt; barrier ----
#pragma unroll
    for (int n = 0; n < 2; n++) { bB[n][0] = RD(0, 49152, wnB + 32 + n * 16, 0); bB[n][1] = RD(0, 49152, wnB + 32 + n * 16, 1); }
    if (more) { STG_G(0, t0 + 2, 0); STG_G(1, t0 + 2, 0); }
    BARRIER; WAITLGKM;
    __builtin_amdgcn_s_setprio(1); MFMAQ(accU, 0, 2, a, bB); __builtin_amdgcn_s_setprio(0);
    if (more) { VMC6; } else { VMC0; }
    BARRIER;
    // ---- P5: tile t0+1/buf1: read A(all)+G(n0-1); stage U(t0+2)->buf0 ----
#pragma unroll
    for (int m = 0; m < 4; m++) { a[m][0] = RD(1, 0, wmB + m * 16, 0); a[m][1] = RD(1, 0, wmB + m * 16, 1); }
#pragma unroll
    for (int n = 0; n < 2; n++) { bA[n][0] = RD(1, 32768, wnB + n * 16, 0); bA[n][1] = RD(1, 32768, wnB + n * 16, 1); }
    if (more) { STG_U(0, t0 + 2, 0); STG_U(1, t0 + 2, 0); }
    BARRIER; WAITLGKM;
    __builtin_amdgcn_s_setprio(1); MFMAQ(accG, 0, 0, a, bA); __builtin_amdgcn_s_setprio(0);
    BARRIER;
    // ---- P6: read G(n2-3); stage A(t0+3) 0,1 -> buf1 ----
#pragma unroll
    for (int n = 0; n < 2; n++) { bB[n][0] = RD(1, 32768, wnB + 32 + n * 16, 0); bB[n][1] = RD(1, 32768, wnB + 32 + n * 16, 1); }
    if (more) { STG_A(0, t0 + 3, 1); STG_A(1, t0 + 3, 1); }
    BARRIER; WAITLGKM;
    __builtin_amdgcn_s_setprio(1); MFMAQ(accG, 0, 2, a, bB); __builtin_amdgcn_s_setprio(0);
    BARRIER;
    // ---- P7: read U(n0-1); stage A(t0+3) 2,3 ----
#pragma unroll
    for (int n = 0; n < 2; n++) { bA[n][0] = RD(1, 49152, wnB + n * 16, 0); bA[n][1] = RD(1, 49152, wnB + n * 16, 1); }
    if (more) { STG_A(2, t0 + 3, 1); STG_A(3, t0 + 3, 1); }
    BARRIER; WAITLGKM;
    __builtin_amdgcn_s_setprio(1); MFMAQ(accU, 0, 0, a, bA); __builtin_amdgcn_s_setprio(0);
    BARRIER;
    // ---- P8: read U(n2-3); stage G(t0+3); vmcnt; barrier ----
#pragma unroll
    for (int n = 0; n < 2; n++) { bB[n][0] = RD(1, 49152, wnB + 32 + n * 16, 0); bB[n][1] = RD(1, 49152, wnB + 32 + n * 16, 1); }
    if (more) { STG_G(0, t0 + 3, 1); STG_G(1, t0 + 3, 1); }
    BARRIER; WAITLGKM;
    __builtin_amdgcn_s_setprio(1); MFMAQ(accU, 0, 2, a, bB); __builtin_amdgcn_s_setprio(0);
    if (more) { VMC6; } else { VMC0; }
    BARRIER;
  }
#undef STG_A
#undef STG_G
#undef STG_U

  // epilogue: act = bf16(silu(g) * u). C layout: col=lane&15, row=(lane>>4)*4+i.
  const int rb = row0 + wmB + ((lane >> 4) << 2);
  const int cb = tn * 128 + wnB + fr;
#pragma unroll
  for (int m = 0; m < 4; m++)
#pragma unroll
    for (int i = 0; i < 4; i++) {
      int r = rb + m * 16 + i;
      __hip_bfloat16* dst = act + (size_t)r * ID + cb;
#pragma unroll
      for (int n = 0; n < 4; n++) {
        float g = accG[m][n][i], uu = accU[m][n][i];
        float s = g / (1.0f + __expf(-g));
        dst[n * 16] = __float2bfloat16(s * uu);
      }
    }
}

// =================== GEMM2: y = act @ Wd[e]^T, 256x128 tile, 4-phase ===================
// LDS: per buffer 48KB: A[256x64] @0, B[128x64] @32768; x2 buffers (96KB).
// 8 waves: 4M x 2N, per-wave 64x64 output.
// Ledger: 6 loads/tile. Per tile T: A j012 issued 3 phases before its P-read,
// A j3 + B j01 issued 2 phases before. VMC3 at end of P2/P4 confirms the full
// 6-load set of the tile consumed in the next phase, leaving 3 newest in flight.
__global__ __launch_bounds__(512, 2) void gemm2_kernel(
    const __hip_bfloat16* __restrict__ act, const __hip_bfloat16* __restrict__ Wd,
    const int* __restrict__ ofs, float* __restrict__ ybuf) {
  __shared__ __align__(128) char lds[98304];
  const int nwg = gridDim.x;              // 576 (div by 8)
  int wg0 = blockIdx.x;
  int wg = (wg0 & 7) * (nwg >> 3) + (wg0 >> 3);
  const int tm = wg >> 3, tn = wg & 7;    // NTN = 8 (128-col tiles over HD=1024)
  const int Rtot = ofs[NE];
  const int row0 = tm * 256;
  if (row0 >= Rtot) return;
  int e = 0;
#pragma unroll
  for (int i = 1; i < NE; i++) e += (row0 >= ofs[i]);
  const int tid = threadIdx.x, wid = tid >> 6, lane = tid & 63;
  const int wm = wid >> 1, wn = wid & 1;  // 4 M-warps x 2 N-warps
  const int fr = lane & 15, fkE = (lane >> 4) << 3;
  const int wmB = wm * 64, wnB = wn * 64;

  const char* srcA[4]; const char* srcB[2];
  int ldA[4], ldB[2];
#pragma unroll
  for (int j = 0; j < 4; j++) {
    int d = j * 8192 + tid * 16;
    int row = d >> 7;
    int kb = (d ^ (((d >> 7) & 7) << 4)) & 127;
    srcA[j] = (const char*)(act + (size_t)(row0 + row) * ID) + kb;
    ldA[j] = j * 8192 + wid * 1024;
  }
#pragma unroll
  for (int j = 0; j < 2; j++) {
    int d = j * 8192 + tid * 16;
    int row = d >> 7;
    int kb = (d ^ (((d >> 7) & 7) << 4)) & 127;
    srcB[j] = (const char*)(Wd + ((size_t)e * HD + tn * 128 + row) * ID) + kb;
    ldB[j] = 32768 + j * 8192 + wid * 1024;
  }
#define STG_A2(j, t, bf) stage16(srcA[j] + (size_t)(t) * 128, (char*)lds + (bf) * 49152 + ldA[j])
#define STG_B2(j, t, bf) stage16(srcB[j] + (size_t)(t) * 128, (char*)lds + (bf) * 49152 + ldB[j])

  auto RD = [&](int bf, int poff, int rowi, int kki) -> short8v {
    int o = ((rowi + fr) << 7) + ((kki << 5) + fkE) * 2;
    o ^= ((o >> 7) & 7) << 4;
    return *(const short8v*)(&lds[bf * 49152 + poff + o]);
  };

  f32x4 acc[4][4];
#pragma unroll
  for (int m = 0; m < 4; m++)
#pragma unroll
    for (int n = 0; n < 4; n++) acc[m][n] = (f32x4)(0.0f);

  const int NT = ID / 64;  // 64 K-tiles
  // prologue: tile0 (A all + B all) -> buf0; A(1) j012 -> buf1; VMC3 waits tile0's 6.
#pragma unroll
  for (int j = 0; j < 4; j++) STG_A2(j, 0, 0);
  STG_B2(0, 0, 0); STG_B2(1, 0, 0);
  STG_A2(0, 1, 1); STG_A2(1, 1, 1); STG_A2(2, 1, 1);
  VMC3; BARRIER;

#pragma unroll 1
  for (int I = 0; I < NT / 2; ++I) {
    const int T = 2 * I;
    const bool more = (T + 2 < NT);
    short8v a[4][2], b0[2][2], b1[2][2];
    // ---- P1: buf0: read A(T) all + B(T) lo; stage A(T+1)j3, B(T+1)j01 -> buf1 ----
#pragma unroll
    for (int m = 0; m < 4; m++) { a[m][0] = RD(0, 0, wmB + m * 16, 0); a[m][1] = RD(0, 0, wmB + m * 16, 1); }
#pragma unroll
    for (int n = 0; n < 2; n++) { b0[n][0] = RD(0, 32768, wnB + n * 16, 0); b0[n][1] = RD(0, 32768, wnB + n * 16, 1); }
    STG_A2(3, T + 1, 1); STG_B2(0, T + 1, 1); STG_B2(1, T + 1, 1);
    BARRIER; WAITLGKM;
    __builtin_amdgcn_s_setprio(1); MFMAQ(acc, 0, 0, a, b0); __builtin_amdgcn_s_setprio(0);
    BARRIER;
    // ---- P2: read B(T) hi; stage A(T+2) j012 -> buf0; VMC3 ----
#pragma unroll
    for (int n = 0; n < 2; n++) { b1[n][0] = RD(0, 32768, wnB + 32 + n * 16, 0); b1[n][1] = RD(0, 32768, wnB + 32 + n * 16, 1); }
    if (more) { STG_A2(0, T + 2, 0); STG_A2(1, T + 2, 0); STG_A2(2, T + 2, 0); }
    BARRIER; WAITLGKM;
    __builtin_amdgcn_s_setprio(1); MFMAQ(acc, 0, 2, a, b1); __builtin_amdgcn_s_setprio(0);
    if (more) { VMC3; } else { VMC0; }
    BARRIER;
    // ---- P3: buf1: read A(T+1) all + B(T+1) lo; stage A(T+2)j3, B(T+2)j01 -> buf0 ----
#pragma unroll
    for (int m = 0; m < 4; m++) { a[m][0] = RD(1, 0, wmB + m * 16, 0); a[m][1] = RD(1, 0, wmB + m * 16, 1); }
#pragma unroll
    for (int n = 0; n < 2; n++) { b0[n][0] = RD(1, 32768, wnB + n * 16, 0); b0[n][1] = RD(1, 32768, wnB + n * 16, 1); }
    if (more) { STG_A2(3, T + 2, 0); STG_B2(0, T + 2, 0); STG_B2(1, T + 2, 0); }
    BARRIER; WAITLGKM;
    __builtin_amdgcn_s_setprio(1); MFMAQ(acc, 0, 0, a, b0); __builtin_amdgcn_s_setprio(0);
    BARRIER;
    // ---- P4: read B(T+1) hi; stage A(T+3) j012 -> buf1; VMC3 ----
#pragma unroll
    for (int n = 0; n < 2; n++) { b1[n][0] = RD(1, 32768, wnB + 32 + n * 16, 0); b1[n][1] = RD(1, 32768, wnB + 32 + n * 16, 1); }
    if (more) { STG_A2(0, T + 3, 1); STG_A2(1, T + 3, 1); STG_A2(2, T + 3, 1); }
    BARRIER; WAITLGKM;
    __builtin_amdgcn_s_setprio(1); MFMAQ(acc, 0, 2, a, b1); __builtin_amdgcn_s_setprio(0);
    if (more) { VMC3; } else { VMC0; }
    BARRIER;
  }
#undef STG_A2
#undef STG_B2

  const int rb = row0 + wmB + ((lane >> 4) << 2);
  const int cb = tn * 128 + wnB + fr;
#pragma unroll
  for (int m = 0; m < 4; m++)
#pragma unroll
    for (int i = 0; i < 4; i++) {
      int r = rb + m * 16 + i;
      float* dst = ybuf + (size_t)r * HD + cb;
#pragma unroll
      for (int n = 0; n < 4; n++) dst[n * 16] = acc[m][n][i];
    }
}

// ---------------- combine: out[t] = w0*y[slot0] + w1*y[slot1] ----------------
__global__ __launch_bounds__(256) void combine_kernel(
    const float* __restrict__ ybuf, const int* __restrict__ slots,
    const float* __restrict__ tw, float* __restrict__ out) {
  int t = blockIdx.x * 4 + (threadIdx.x >> 6);
  int lane = threadIdx.x & 63;
  int r0 = slots[t * 2 + 0], r1 = slots[t * 2 + 1];
  float w0 = tw[t * 2 + 0], w1 = tw[t * 2 + 1];
  const float4* y0 = (const float4*)(ybuf + (size_t)r0 * HD);
  const float4* y1 = (const float4*)(ybuf + (size_t)r1 * HD);
  float4* o = (float4*)(out + (size_t)t * HD);
#pragma unroll
  for (int j = 0; j < 4; j++) {
    int ix = j * 64 + lane;
    float4 a = y0[ix], b = y1[ix];
    float4 c;
    c.x = w0 * a.x + w1 * b.x; c.y = w0 * a.y + w1 * b.y;
    c.z = w0 * a.z + w1 * b.z; c.w = w0 * a.w + w1 * b.w;
    o[ix] = c;
  }
}

extern "C" void kernel_launch(void* const* d_in, const int* in_sizes, int n_in,
                              void* d_out, int out_size, void* d_ws, size_t ws_size,
                              hipStream_t stream) {
  (void)in_sizes; (void)n_in; (void)out_size; (void)ws_size;
  const float* h  = (const float*)d_in[0];
  const float* rw = (const float*)d_in[1];
  const float* gw = (const float*)d_in[2];
  const float* uw = (const float*)d_in[3];
  const float* dw = (const float*)d_in[4];
  float* out = (float*)d_out;

  char* ws = (char*)d_ws;
  size_t off = 0;
  auto alloc = [&](size_t bytes) { char* p = ws + off; off += (bytes + 255) & ~255ULL; return p; };
  __hip_bfloat16* wg  = (__hip_bfloat16*)alloc((size_t)NE * ID * HD * 2);
  __hip_bfloat16* wu  = (__hip_bfloat16*)alloc((size_t)NE * ID * HD * 2);
  __hip_bfloat16* wd  = (__hip_bfloat16*)alloc((size_t)NE * HD * ID * 2);
  __hip_bfloat16* act = (__hip_bfloat16*)alloc((size_t)RMAX * ID * 2);
  __hip_bfloat16* hx  = (__hip_bfloat16*)alloc((size_t)TOKENS * HD * 2);
  float* ybuf = (float*)alloc((size_t)RMAX * HD * 4);
  __hip_bfloat16* zrow = (__hip_bfloat16*)alloc(HD * 2);
  int* rowmap = (int*)alloc(RMAX * 4);
  int* tidx   = (int*)alloc(TOKENS * 2 * 4);
  float* twt  = (float*)alloc(TOKENS * 2 * 4);
  int* slots  = (int*)alloc(TOKENS * 2 * 4);
  int* cnt    = (int*)alloc(256);
  int* cnt2   = (int*)alloc(256);
  int* ofs    = (int*)alloc(256);

  hipMemsetAsync(cnt, 0, NE * 4, stream);
  hipMemsetAsync(rowmap, 0xFF, RMAX * 4, stream);
  hipMemsetAsync(zrow, 0, HD * 2, stream);

  convert_kernel<<<16384, 256, 0, stream>>>(gw, wg);
  convert_kernel<<<16384, 256, 0, stream>>>(uw, wu);
  convert_kernel<<<16384, 256, 0, stream>>>(dw, wd);
  router_kernel<<<TOKENS / 4, 256, 0, stream>>>(h, rw, hx, tidx, twt, cnt);
  scan_kernel<<<1, 64, 0, stream>>>(cnt, ofs, cnt2);
  scatter_kernel<<<TOKENS / 256, 256, 0, stream>>>(tidx, twt, ofs, cnt2, rowmap, slots);
  gemm1_kernel<<<MAXT * 32, 512, 0, stream>>>(hx, wg, wu, rowmap, ofs, zrow, act);
  gemm2_kernel<<<MAXT * 8, 512, 0, stream>>>(act, wd, ofs, ybuf);
  combine_kernel<<<TOKENS / 4, 256, 0, stream>>>(ybuf, slots, twt, out);
}